// Round 2
// baseline (3415.479 us; speedup 1.0000x reference)
//
#include <hip/hip_runtime.h>

// ---------------------------------------------------------------------------
// SpikingMLP forward, fp32 baseline. (Resubmit — round 1 infra failure.)
// T=8, B=64, F0=32768, D=2048, NC=1000. Rows R = T*B = 512, layout r = t*B+b.
// ---------------------------------------------------------------------------

#define T_STEPS 8
#define BATCH 64
#define F0 32768
#define DIM 2048
#define NROWS 512   // T*B

#define BM 64
#define BN 64
#define BK 32

// C[M,N] = A[M,K] * W[N,K]^T + bias[N]
__global__ __launch_bounds__(256) void gemm_bias_kernel(
    const float* __restrict__ A, const float* __restrict__ W,
    const float* __restrict__ bias, float* __restrict__ C,
    int M, int N, int K)
{
    __shared__ float As[BK][BM + 4];
    __shared__ float Ws[BK][BN + 4];
    const int bm = blockIdx.y * BM;
    const int bn = blockIdx.x * BN;
    const int tid = threadIdx.x;
    const int tx = tid & 15;
    const int ty = tid >> 4;

    float acc[4][4] = {{0.f, 0.f, 0.f, 0.f}, {0.f, 0.f, 0.f, 0.f},
                       {0.f, 0.f, 0.f, 0.f}, {0.f, 0.f, 0.f, 0.f}};

    const int srow = tid >> 3;   // 0..31
    const int scol4 = tid & 7;   // 0..7  -> float4 column within BK

    const int ktiles = K / BK;
    for (int kt = 0; kt < ktiles; ++kt) {
        const int k0 = kt * BK;
#pragma unroll
        for (int h = 0; h < 2; ++h) {
            const int row = srow + h * 32;
            // A tile (transposed into LDS)
            {
                const int gr = bm + row;
                float4 v = make_float4(0.f, 0.f, 0.f, 0.f);
                if (gr < M)
                    v = *reinterpret_cast<const float4*>(&A[(size_t)gr * K + k0 + scol4 * 4]);
                As[scol4 * 4 + 0][row] = v.x;
                As[scol4 * 4 + 1][row] = v.y;
                As[scol4 * 4 + 2][row] = v.z;
                As[scol4 * 4 + 3][row] = v.w;
            }
            // W tile (transposed into LDS)
            {
                const int gr = bn + row;
                float4 v = make_float4(0.f, 0.f, 0.f, 0.f);
                if (gr < N)
                    v = *reinterpret_cast<const float4*>(&W[(size_t)gr * K + k0 + scol4 * 4]);
                Ws[scol4 * 4 + 0][row] = v.x;
                Ws[scol4 * 4 + 1][row] = v.y;
                Ws[scol4 * 4 + 2][row] = v.z;
                Ws[scol4 * 4 + 3][row] = v.w;
            }
        }
        __syncthreads();
#pragma unroll
        for (int kk = 0; kk < BK; ++kk) {
            const float4 a = *reinterpret_cast<const float4*>(&As[kk][ty * 4]);
            const float4 w = *reinterpret_cast<const float4*>(&Ws[kk][tx * 4]);
            const float av[4] = {a.x, a.y, a.z, a.w};
            const float wv[4] = {w.x, w.y, w.z, w.w};
#pragma unroll
            for (int i = 0; i < 4; ++i)
#pragma unroll
                for (int j = 0; j < 4; ++j)
                    acc[i][j] += av[i] * wv[j];
        }
        __syncthreads();
    }

#pragma unroll
    for (int i = 0; i < 4; ++i) {
        const int gr = bm + ty * 4 + i;
        if (gr < M) {
#pragma unroll
            for (int j = 0; j < 4; ++j) {
                const int gc = bn + tx * 4 + j;
                if (gc < N) C[(size_t)gr * N + gc] = acc[i][j] + bias[gc];
            }
        }
    }
}

// IF neuron on raw input: x [T,B,F0] -> spikes s0 [T*B, F0]
__global__ __launch_bounds__(256) void if0_kernel(
    const float* __restrict__ x, float* __restrict__ s)
{
    const size_t id = (size_t)blockIdx.x * blockDim.x + threadIdx.x; // b*F0+f
    float v = 0.f;
#pragma unroll
    for (int t = 0; t < T_STEPS; ++t) {
        const size_t idx = (size_t)t * (BATCH * (size_t)F0) + id;
        v += x[idx];
        if (v >= 1.0f) { s[idx] = 1.0f; v = 0.f; }
        else           { s[idx] = 0.f; }
    }
}

// BatchNorm stats over the 512-row batch -> scale/shift per feature
__global__ __launch_bounds__(256) void bn_stats_kernel(
    const float* __restrict__ z, const float* __restrict__ g,
    const float* __restrict__ be, float* __restrict__ scale,
    float* __restrict__ shift)
{
    const int o = blockIdx.x * blockDim.x + threadIdx.x; // 0..2047
    float sum = 0.f, sumsq = 0.f;
#pragma unroll 8
    for (int r = 0; r < NROWS; ++r) {
        const float v = z[(size_t)r * DIM + o];
        sum += v;
        sumsq += v * v;
    }
    const float mean = sum * (1.0f / NROWS);
    const float var = sumsq * (1.0f / NROWS) - mean * mean;
    const float inv = rsqrtf(var + 1e-5f);
    const float sc = g[o] * inv;
    scale[o] = sc;
    shift[o] = be[o] - mean * sc;
}

// Apply BN then IF neuron over T: z [T*B, D] -> spikes s [T*B, D]
__global__ __launch_bounds__(256) void bn_if_kernel(
    const float* __restrict__ z, const float* __restrict__ scale,
    const float* __restrict__ shift, float* __restrict__ s)
{
    const int id = blockIdx.x * blockDim.x + threadIdx.x; // b*D+o, 0..131071
    const int o = id & (DIM - 1);
    const float sc = scale[o];
    const float sh = shift[o];
    float v = 0.f;
#pragma unroll
    for (int t = 0; t < T_STEPS; ++t) {
        const size_t idx = (size_t)t * (BATCH * DIM) + id;
        const float zt = z[idx] * sc + sh;
        v += zt;
        if (v >= 1.0f) { s[idx] = 1.0f; v = 0.f; }
        else           { s[idx] = 0.f; }
    }
}

// Mean of spikes over T: s3 [T*B, D] -> sbar [B, D]
__global__ __launch_bounds__(256) void sbar_kernel(
    const float* __restrict__ s3, float* __restrict__ sbar)
{
    const int id = blockIdx.x * blockDim.x + threadIdx.x; // b*D+o
    float acc = 0.f;
#pragma unroll
    for (int t = 0; t < T_STEPS; ++t)
        acc += s3[(size_t)t * (BATCH * DIM) + id];
    sbar[id] = acc * (1.0f / T_STEPS);
}

extern "C" void kernel_launch(void* const* d_in, const int* in_sizes, int n_in,
                              void* d_out, int out_size, void* d_ws, size_t ws_size,
                              hipStream_t stream)
{
    const float* x    = (const float*)d_in[0];
    const float* W0   = (const float*)d_in[1];
    const float* b0   = (const float*)d_in[2];
    const float* g0   = (const float*)d_in[3];
    const float* be0  = (const float*)d_in[4];
    const float* W1   = (const float*)d_in[5];
    const float* b1   = (const float*)d_in[6];
    const float* g1   = (const float*)d_in[7];
    const float* be1  = (const float*)d_in[8];
    const float* W2   = (const float*)d_in[9];
    const float* b2   = (const float*)d_in[10];
    const float* g2   = (const float*)d_in[11];
    const float* be2  = (const float*)d_in[12];
    const float* Wout = (const float*)d_in[13];
    const float* bout = (const float*)d_in[14];
    float* out = (float*)d_out;

    char* ws = (char*)d_ws;
    size_t off = 0;
    auto alloc = [&](size_t nfloats) {
        float* p = (float*)(ws + off);
        off += (nfloats * sizeof(float) + 255) & ~(size_t)255;
        return p;
    };
    float* s0    = alloc((size_t)NROWS * F0);   // 67 MB
    float* z     = alloc((size_t)NROWS * DIM);  // 4 MB (reused per layer)
    float* s1    = alloc((size_t)NROWS * DIM);
    float* s2    = alloc((size_t)NROWS * DIM);
    float* s3    = alloc((size_t)NROWS * DIM);
    float* scale = alloc(DIM);
    float* shift = alloc(DIM);
    float* sb    = alloc((size_t)BATCH * DIM);
    (void)ws_size; (void)in_sizes; (void)n_in; (void)out_size;

    // sn0
    if0_kernel<<<(BATCH * (size_t)F0) / 256, 256, 0, stream>>>(x, s0);

    // layer 0: fc -> bn -> if
    gemm_bias_kernel<<<dim3(DIM / BN, NROWS / BM), 256, 0, stream>>>(
        s0, W0, b0, z, NROWS, DIM, F0);
    bn_stats_kernel<<<DIM / 256, 256, 0, stream>>>(z, g0, be0, scale, shift);
    bn_if_kernel<<<(BATCH * DIM) / 256, 256, 0, stream>>>(z, scale, shift, s1);

    // layer 1
    gemm_bias_kernel<<<dim3(DIM / BN, NROWS / BM), 256, 0, stream>>>(
        s1, W1, b1, z, NROWS, DIM, DIM);
    bn_stats_kernel<<<DIM / 256, 256, 0, stream>>>(z, g1, be1, scale, shift);
    bn_if_kernel<<<(BATCH * DIM) / 256, 256, 0, stream>>>(z, scale, shift, s2);

    // layer 2
    gemm_bias_kernel<<<dim3(DIM / BN, NROWS / BM), 256, 0, stream>>>(
        s2, W2, b2, z, NROWS, DIM, DIM);
    bn_stats_kernel<<<DIM / 256, 256, 0, stream>>>(z, g2, be2, scale, shift);
    bn_if_kernel<<<(BATCH * DIM) / 256, 256, 0, stream>>>(z, scale, shift, s3);

    // readout: mean over T folded into A, then [64,2048] x [1000,2048]^T
    sbar_kernel<<<(BATCH * DIM) / 256, 256, 0, stream>>>(s3, sb);
    gemm_bias_kernel<<<dim3((1000 + BN - 1) / BN, 1), 256, 0, stream>>>(
        sb, Wout, bout, out, BATCH, 1000, DIM);
}

// Round 3
// 429.129 us; speedup vs baseline: 7.9591x; 7.9591x over previous
//
#include <hip/hip_runtime.h>

// ---------------------------------------------------------------------------
// SpikingMLP forward. bf16 MFMA GEMMs with split-precision weights:
// W = W_hi(bf16) + W_lo(bf16 of residual), converted in-kernel during staging.
// Spikes are exact in bf16, so A*W_hi + A*W_lo ~ fp32-grade accuracy.
// T=8, B=64, F0=32768, D=2048, NC=1000, rows R=T*B=512.
// ---------------------------------------------------------------------------

#define T_STEPS 8
#define BATCH 64
#define F0 32768
#define DIM 2048
#define NROWS 512
#define NC 1000

typedef __attribute__((ext_vector_type(8))) short short8;   // 8 bf16 (4 VGPR)
typedef __attribute__((ext_vector_type(4))) float f32x4;    // MFMA acc

__device__ __forceinline__ unsigned short bf16_rne(float f) {
    unsigned int u = __float_as_uint(f);
    u += 0x7FFFu + ((u >> 16) & 1u);
    return (unsigned short)(u >> 16);
}

// ---------------------------------------------------------------------------
// Split-K GEMM: part[z][m][n] = sum_{k in split z} A[m][k] * W[n][k]
// A: bf16 (ushort bits) [Mpad>=BM*gridx][K], W: fp32 [Wrows][K] row-clamped.
// Tile 128x128x64, 4 waves, 16x16x32 bf16 MFMA, acc += A*W_hi + A*W_lo.
// LDS XOR-swizzled (byte ^= (row&7)<<4) on both write/stage and read sides.
// ---------------------------------------------------------------------------
#define BM 128
#define BN 128
#define BK 64

__device__ __forceinline__ short8 lds_frag(const unsigned short* base, int row, int kb) {
    const int off = row * 128 + (kb ^ ((row & 7) << 4));
    return *(const short8*)((const char*)base + off);
}

__global__ __launch_bounds__(256) void gemm_splitk(
    const unsigned short* __restrict__ A, const float* __restrict__ W,
    float* __restrict__ part, int M, int N, int K, int Kpart, int Wrows)
{
    __shared__ unsigned short As[BM * BK];   // 16 KB
    __shared__ unsigned short Hs[BN * BK];   // 16 KB (W hi)
    __shared__ unsigned short Ls[BN * BK];   // 16 KB (W lo)

    const int tid  = threadIdx.x;
    const int lane = tid & 63;
    const int w    = tid >> 6;
    const int bm   = blockIdx.x * BM;
    const int bn   = blockIdx.y * BN;
    const int kz   = blockIdx.z;
    const int ksteps = Kpart / BK;

    const int wm = (w >> 1) * 64;
    const int wn = (w & 1) * 64;

    f32x4 acc[4][4] = {};

    for (int kt = 0; kt < ksteps; ++kt) {
        const int k0 = kz * Kpart + kt * BK;

        // ---- A tile: global_load_lds, 4 calls/wave, linear dst + XOR'd src ----
#pragma unroll
        for (int c = 0; c < 4; ++c) {
            const int r    = w * 32 + c * 8 + (lane >> 3);
            const int colb = ((lane & 7) * 16) ^ ((r & 7) << 4);
            const char* src = (const char*)A + ((size_t)(bm + r) * K + k0) * 2 + colb;
            unsigned short* dst = &As[(w * 32 + c * 8) * BK];
            __builtin_amdgcn_global_load_lds(
                (const __attribute__((address_space(1))) void*)src,
                (__attribute__((address_space(3))) void*)dst, 16, 0, 0);
        }

        // ---- W tile: fp32 loads -> hi/lo bf16 split -> swizzled ds_write ----
        float4 wv[8];
#pragma unroll
        for (int i = 0; i < 8; ++i) {
            const int q  = tid + 256 * i;
            const int n  = q >> 4;
            const int c4 = q & 15;
            const int gn = min(bn + n, Wrows - 1);
            wv[i] = *(const float4*)&W[(size_t)gn * K + k0 + c4 * 4];
        }
#pragma unroll
        for (int i = 0; i < 8; ++i) {
            const int q  = tid + 256 * i;
            const int n  = q >> 4;
            const int c4 = q & 15;
            const float vf[4] = {wv[i].x, wv[i].y, wv[i].z, wv[i].w};
            unsigned short h[4], l[4];
#pragma unroll
            for (int e = 0; e < 4; ++e) {
                h[e] = bf16_rne(vf[e]);
                const float hf = __uint_as_float((unsigned int)h[e] << 16);
                l[e] = bf16_rne(vf[e] - hf);
            }
            const int off = n * 128 + (((c4 * 8)) ^ ((n & 7) << 4));
            *(ushort4*)((char*)Hs + off) = make_ushort4(h[0], h[1], h[2], h[3]);
            *(ushort4*)((char*)Ls + off) = make_ushort4(l[0], l[1], l[2], l[3]);
        }

        __syncthreads();   // drains vmcnt (A dma) + lgkmcnt (W ds_writes)

        // ---- MFMA: acc += A*Whi + A*Wlo ----
#pragma unroll
        for (int kk = 0; kk < 2; ++kk) {
            const int kb = (kk * 32 + (lane >> 4) * 8) * 2;   // byte offset along K
            short8 a[4], bh[4], bl[4];
#pragma unroll
            for (int i = 0; i < 4; ++i)
                a[i] = lds_frag(As, wm + i * 16 + (lane & 15), kb);
#pragma unroll
            for (int i = 0; i < 4; ++i) {
                const int r = wn + i * 16 + (lane & 15);
                bh[i] = lds_frag(Hs, r, kb);
                bl[i] = lds_frag(Ls, r, kb);
            }
#pragma unroll
            for (int mi = 0; mi < 4; ++mi)
#pragma unroll
                for (int ni = 0; ni < 4; ++ni) {
                    acc[mi][ni] = __builtin_amdgcn_mfma_f32_16x16x32_bf16(
                        a[mi], bh[ni], acc[mi][ni], 0, 0, 0);
                    acc[mi][ni] = __builtin_amdgcn_mfma_f32_16x16x32_bf16(
                        a[mi], bl[ni], acc[mi][ni], 0, 0, 0);
                }
        }
        __syncthreads();
    }

    // ---- epilogue: partial store (C/D layout: col=lane&15, row=(lane>>4)*4+e) ----
    const size_t zoff = (size_t)kz * M * N;
#pragma unroll
    for (int mi = 0; mi < 4; ++mi) {
        const int gr0 = bm + wm + mi * 16 + (lane >> 4) * 4;
#pragma unroll
        for (int ni = 0; ni < 4; ++ni) {
            const int gc = bn + wn + ni * 16 + (lane & 15);
            if (gc < N) {
#pragma unroll
                for (int e = 0; e < 4; ++e) {
                    const int gr = gr0 + e;
                    if (gr < M) part[zoff + (size_t)gr * N + gc] = acc[mi][ni][e];
                }
            }
        }
    }
}

// part[KS][.][N] summed + bias -> out (fp32)
__global__ __launch_bounds__(256) void reduce_bias(
    const float* __restrict__ part, const float* __restrict__ bias,
    float* __restrict__ out, int KS, int MN, int N)
{
    const int i4 = blockIdx.x * 256 + threadIdx.x;
    if (i4 * 4 >= MN) return;
    float4 s = make_float4(0.f, 0.f, 0.f, 0.f);
    for (int z = 0; z < KS; ++z) {
        const float4 p = *(const float4*)&part[(size_t)z * MN + i4 * 4];
        s.x += p.x; s.y += p.y; s.z += p.z; s.w += p.w;
    }
    const int col = (i4 * 4) % N;
    const float4 b = *(const float4*)&bias[col];
    s.x += b.x; s.y += b.y; s.z += b.z; s.w += b.w;
    *(float4*)&out[(size_t)i4 * 4] = s;
}

// IF neuron on raw input: x [T,B,F0] fp32 -> spikes bf16 bits
__global__ __launch_bounds__(256) void if0_kernel(
    const float* __restrict__ x, unsigned short* __restrict__ s)
{
    const size_t id = (size_t)blockIdx.x * blockDim.x + threadIdx.x;
    float v = 0.f;
#pragma unroll
    for (int t = 0; t < T_STEPS; ++t) {
        const size_t idx = (size_t)t * (BATCH * (size_t)F0) + id;
        v += x[idx];
        if (v >= 1.0f) { s[idx] = 0x3F80; v = 0.f; }
        else           { s[idx] = 0; }
    }
}

// BN stats over 512 rows: block = 64 features, 4 row-quarters per thread
__global__ __launch_bounds__(256) void bn_stats(
    const float* __restrict__ z, const float* __restrict__ g,
    const float* __restrict__ be, float* __restrict__ scale,
    float* __restrict__ shift)
{
    __shared__ float ssum[4][64], ssq[4][64];
    const int l = threadIdx.x & 63;
    const int q = threadIdx.x >> 6;
    const int f = blockIdx.x * 64 + l;
    float sum = 0.f, sq = 0.f;
    for (int r = q; r < NROWS; r += 4) {
        const float v = z[(size_t)r * DIM + f];
        sum += v; sq += v * v;
    }
    ssum[q][l] = sum; ssq[q][l] = sq;
    __syncthreads();
    if (threadIdx.x < 64) {
        float ts = 0.f, tq = 0.f;
#pragma unroll
        for (int i = 0; i < 4; ++i) { ts += ssum[i][l]; tq += ssq[i][l]; }
        const float mean = ts * (1.0f / NROWS);
        const float var  = tq * (1.0f / NROWS) - mean * mean;
        const float inv  = rsqrtf(var + 1e-5f);
        const float sc   = g[f] * inv;
        scale[f] = sc;
        shift[f] = be[f] - mean * sc;
    }
}

// BN apply + IF neuron: z fp32 [T*B, D] -> spikes bf16 bits
__global__ __launch_bounds__(256) void bn_if(
    const float* __restrict__ z, const float* __restrict__ scale,
    const float* __restrict__ shift, unsigned short* __restrict__ s)
{
    const int id = blockIdx.x * blockDim.x + threadIdx.x;
    const int o  = id & (DIM - 1);
    const float sc = scale[o];
    const float sh = shift[o];
    float v = 0.f;
#pragma unroll
    for (int t = 0; t < T_STEPS; ++t) {
        const size_t idx = (size_t)t * (BATCH * DIM) + id;
        v += z[idx] * sc + sh;
        if (v >= 1.0f) { s[idx] = 0x3F80; v = 0.f; }
        else           { s[idx] = 0; }
    }
}

// Mean spikes over T -> bf16 (k/8 exact)
__global__ __launch_bounds__(256) void sbar_kernel(
    const unsigned short* __restrict__ s3, unsigned short* __restrict__ sbar)
{
    const int id = blockIdx.x * blockDim.x + threadIdx.x;
    int cnt = 0;
#pragma unroll
    for (int t = 0; t < T_STEPS; ++t)
        cnt += (s3[(size_t)t * (BATCH * DIM) + id] >> 7) & 1;
    sbar[id] = bf16_rne((float)cnt * 0.125f);
}

extern "C" void kernel_launch(void* const* d_in, const int* in_sizes, int n_in,
                              void* d_out, int out_size, void* d_ws, size_t ws_size,
                              hipStream_t stream)
{
    const float* x    = (const float*)d_in[0];
    const float* W0   = (const float*)d_in[1];
    const float* b0   = (const float*)d_in[2];
    const float* g0   = (const float*)d_in[3];
    const float* be0  = (const float*)d_in[4];
    const float* W1   = (const float*)d_in[5];
    const float* b1   = (const float*)d_in[6];
    const float* g1   = (const float*)d_in[7];
    const float* be1  = (const float*)d_in[8];
    const float* W2   = (const float*)d_in[9];
    const float* b2   = (const float*)d_in[10];
    const float* g2   = (const float*)d_in[11];
    const float* be2  = (const float*)d_in[12];
    const float* Wout = (const float*)d_in[13];
    const float* bout = (const float*)d_in[14];
    float* out = (float*)d_out;
    (void)in_sizes; (void)n_in; (void)out_size; (void)ws_size;

    char* ws = (char*)d_ws;
    size_t off = 0;
    auto alloc = [&](size_t nbytes) {
        char* p = ws + off;
        off = (off + nbytes + 255) & ~(size_t)255;
        return p;
    };
    unsigned short* s0 = (unsigned short*)alloc((size_t)NROWS * F0 * 2);  // 33.5 MB
    unsigned short* s1 = (unsigned short*)alloc((size_t)NROWS * DIM * 2);
    unsigned short* s2 = (unsigned short*)alloc((size_t)NROWS * DIM * 2);
    unsigned short* s3 = (unsigned short*)alloc((size_t)NROWS * DIM * 2);
    unsigned short* sb = (unsigned short*)alloc((size_t)128 * DIM * 2);   // padded to 128 rows
    float* z    = (float*)alloc((size_t)NROWS * DIM * 4);
    float* part = (float*)alloc((size_t)8 * NROWS * DIM * 4);             // 33.5 MB
    float* scale = (float*)alloc(DIM * 4);
    float* shift = (float*)alloc(DIM * 4);

    const int MN = NROWS * DIM;

    // sn0
    if0_kernel<<<(BATCH * (size_t)F0) / 256, 256, 0, stream>>>(x, s0);

    // layer 0: K=32768, KS=8
    gemm_splitk<<<dim3(NROWS / BM, DIM / BN, 8), 256, 0, stream>>>(
        s0, W0, part, NROWS, DIM, F0, F0 / 8, DIM);
    reduce_bias<<<MN / 4 / 256, 256, 0, stream>>>(part, b0, z, 8, MN, DIM);
    bn_stats<<<DIM / 64, 256, 0, stream>>>(z, g0, be0, scale, shift);
    bn_if<<<(BATCH * DIM) / 256, 256, 0, stream>>>(z, scale, shift, s1);

    // layer 1: K=2048, KS=4
    gemm_splitk<<<dim3(NROWS / BM, DIM / BN, 4), 256, 0, stream>>>(
        s1, W1, part, NROWS, DIM, DIM, DIM / 4, DIM);
    reduce_bias<<<MN / 4 / 256, 256, 0, stream>>>(part, b1, z, 4, MN, DIM);
    bn_stats<<<DIM / 64, 256, 0, stream>>>(z, g1, be1, scale, shift);
    bn_if<<<(BATCH * DIM) / 256, 256, 0, stream>>>(z, scale, shift, s2);

    // layer 2
    gemm_splitk<<<dim3(NROWS / BM, DIM / BN, 4), 256, 0, stream>>>(
        s2, W2, part, NROWS, DIM, DIM, DIM / 4, DIM);
    reduce_bias<<<MN / 4 / 256, 256, 0, stream>>>(part, b2, z, 4, MN, DIM);
    bn_stats<<<DIM / 64, 256, 0, stream>>>(z, g2, be2, scale, shift);
    bn_if<<<(BATCH * DIM) / 256, 256, 0, stream>>>(z, scale, shift, s3);

    // readout: mean over T first (exact in bf16), then [64,2048]x[1000,2048]^T
    sbar_kernel<<<(BATCH * DIM) / 256, 256, 0, stream>>>(s3, sb);
    gemm_splitk<<<dim3(1, (NC + BN - 1) / BN, 4), 256, 0, stream>>>(
        sb, Wout, part, BATCH, NC, DIM, DIM / 4, NC);
    reduce_bias<<<(BATCH * NC / 4 + 255) / 256, 256, 0, stream>>>(
        part, bout, out, 4, BATCH * NC, NC);
}

// Round 7
// 408.410 us; speedup vs baseline: 8.3629x; 1.0507x over previous
//
#include <hip/hip_runtime.h>

// ---------------------------------------------------------------------------
// SpikingMLP forward. bf16 MFMA GEMMs with split-precision weights
// (W = W_hi + W_lo bf16, converted in-kernel; spikes exact in bf16).
// R4 (3rd resubmit after infra failures): XCD-chunked block swizzle (W
// fetched once from HBM), KS0=16, KS12=8, layer-2 bn_if fused with T-mean.
// ---------------------------------------------------------------------------

#define T_STEPS 8
#define BATCH 64
#define F0 32768
#define DIM 2048
#define NROWS 512
#define NC 1000

typedef __attribute__((ext_vector_type(8))) short short8;   // 8 bf16 (4 VGPR)
typedef __attribute__((ext_vector_type(4))) float f32x4;    // MFMA acc

__device__ __forceinline__ unsigned short bf16_rne(float f) {
    unsigned int u = __float_as_uint(f);
    u += 0x7FFFu + ((u >> 16) & 1u);
    return (unsigned short)(u >> 16);
}

// ---------------------------------------------------------------------------
// Split-K GEMM: part[z][m][n] = sum_{k in split z} A[m][k] * W[n][k]
// Tile 128x128x64, 4 waves, 16x16x32 bf16 MFMA, acc += A*W_hi + A*W_lo.
// LDS XOR-swizzled (byte ^= (row&7)<<4) both sides. XCD-chunked block remap:
// requires gridDim.x*y*z % 8 == 0 (all call sites satisfy this).
// ---------------------------------------------------------------------------
#define BM 128
#define BN 128
#define BK 64

__device__ __forceinline__ short8 lds_frag(const unsigned short* base, int row, int kb) {
    const int off = row * 128 + (kb ^ ((row & 7) << 4));
    return *(const short8*)((const char*)base + off);
}

__global__ __launch_bounds__(256) void gemm_splitk(
    const unsigned short* __restrict__ A, const float* __restrict__ W,
    float* __restrict__ part, int M, int N, int K, int Kpart, int Wrows)
{
    __shared__ unsigned short As[BM * BK];   // 16 KB
    __shared__ unsigned short Hs[BN * BK];   // 16 KB (W hi)
    __shared__ unsigned short Ls[BN * BK];   // 16 KB (W lo)

    // ---- XCD-chunked bijective remap (T1): consecutive work ids share one XCD L2
    const int gx = gridDim.x, gy = gridDim.y;
    const int nwg = gx * gy * gridDim.z;
    const int lid = blockIdx.x + gx * (blockIdx.y + gy * blockIdx.z);
    const int cpx = nwg >> 3;
    const int nid = (lid & 7) * cpx + (lid >> 3);
    const int bx  = nid % gx;
    const int by  = (nid / gx) % gy;
    const int kz  = nid / (gx * gy);

    const int tid  = threadIdx.x;
    const int lane = tid & 63;
    const int w    = tid >> 6;
    const int bm   = bx * BM;
    const int bn   = by * BN;
    const int ksteps = Kpart / BK;

    const int wm = (w >> 1) * 64;
    const int wn = (w & 1) * 64;

    f32x4 acc[4][4] = {};

    for (int kt = 0; kt < ksteps; ++kt) {
        const int k0 = kz * Kpart + kt * BK;

        // ---- A tile: global_load_lds, linear dst + XOR'd src ----
#pragma unroll
        for (int c = 0; c < 4; ++c) {
            const int r    = w * 32 + c * 8 + (lane >> 3);
            const int colb = ((lane & 7) * 16) ^ ((r & 7) << 4);
            const char* src = (const char*)A + ((size_t)(bm + r) * K + k0) * 2 + colb;
            unsigned short* dst = &As[(w * 32 + c * 8) * BK];
            __builtin_amdgcn_global_load_lds(
                (const __attribute__((address_space(1))) void*)src,
                (__attribute__((address_space(3))) void*)dst, 16, 0, 0);
        }

        // ---- W tile: fp32 loads -> hi/lo bf16 split -> swizzled ds_write ----
        float4 wv[8];
#pragma unroll
        for (int i = 0; i < 8; ++i) {
            const int q  = tid + 256 * i;
            const int n  = q >> 4;
            const int c4 = q & 15;
            const int gn = min(bn + n, Wrows - 1);
            wv[i] = *(const float4*)&W[(size_t)gn * K + k0 + c4 * 4];
        }
#pragma unroll
        for (int i = 0; i < 8; ++i) {
            const int q  = tid + 256 * i;
            const int n  = q >> 4;
            const int c4 = q & 15;
            const float vf[4] = {wv[i].x, wv[i].y, wv[i].z, wv[i].w};
            unsigned short h[4], l[4];
#pragma unroll
            for (int e = 0; e < 4; ++e) {
                h[e] = bf16_rne(vf[e]);
                const float hf = __uint_as_float((unsigned int)h[e] << 16);
                l[e] = bf16_rne(vf[e] - hf);
            }
            const int off = n * 128 + (((c4 * 8)) ^ ((n & 7) << 4));
            *(ushort4*)((char*)Hs + off) = make_ushort4(h[0], h[1], h[2], h[3]);
            *(ushort4*)((char*)Ls + off) = make_ushort4(l[0], l[1], l[2], l[3]);
        }

        __syncthreads();

        // ---- MFMA: acc += A*Whi + A*Wlo ----
#pragma unroll
        for (int kk = 0; kk < 2; ++kk) {
            const int kb = (kk * 32 + (lane >> 4) * 8) * 2;
            short8 a[4], bh[4], bl[4];
#pragma unroll
            for (int i = 0; i < 4; ++i)
                a[i] = lds_frag(As, wm + i * 16 + (lane & 15), kb);
#pragma unroll
            for (int i = 0; i < 4; ++i) {
                const int r = wn + i * 16 + (lane & 15);
                bh[i] = lds_frag(Hs, r, kb);
                bl[i] = lds_frag(Ls, r, kb);
            }
#pragma unroll
            for (int mi = 0; mi < 4; ++mi)
#pragma unroll
                for (int ni = 0; ni < 4; ++ni) {
                    acc[mi][ni] = __builtin_amdgcn_mfma_f32_16x16x32_bf16(
                        a[mi], bh[ni], acc[mi][ni], 0, 0, 0);
                    acc[mi][ni] = __builtin_amdgcn_mfma_f32_16x16x32_bf16(
                        a[mi], bl[ni], acc[mi][ni], 0, 0, 0);
                }
        }
        __syncthreads();
    }

    // ---- epilogue: partial store (C/D: col=lane&15, row=(lane>>4)*4+e) ----
    const size_t zoff = (size_t)kz * M * N;
#pragma unroll
    for (int mi = 0; mi < 4; ++mi) {
        const int gr0 = bm + wm + mi * 16 + (lane >> 4) * 4;
#pragma unroll
        for (int ni = 0; ni < 4; ++ni) {
            const int gc = bn + wn + ni * 16 + (lane & 15);
            if (gc < N) {
#pragma unroll
                for (int e = 0; e < 4; ++e) {
                    const int gr = gr0 + e;
                    if (gr < M) part[zoff + (size_t)gr * N + gc] = acc[mi][ni][e];
                }
            }
        }
    }
}

// part[KS][.][N] summed + bias -> out (fp32)
__global__ __launch_bounds__(256) void reduce_bias(
    const float* __restrict__ part, const float* __restrict__ bias,
    float* __restrict__ out, int KS, int MN, int N)
{
    const int i4 = blockIdx.x * 256 + threadIdx.x;
    if (i4 * 4 >= MN) return;
    float4 s = make_float4(0.f, 0.f, 0.f, 0.f);
    for (int z = 0; z < KS; ++z) {
        const float4 p = *(const float4*)&part[(size_t)z * MN + i4 * 4];
        s.x += p.x; s.y += p.y; s.z += p.z; s.w += p.w;
    }
    const int col = (i4 * 4) % N;
    const float4 b = *(const float4*)&bias[col];
    s.x += b.x; s.y += b.y; s.z += b.z; s.w += b.w;
    *(float4*)&out[(size_t)i4 * 4] = s;
}

// IF neuron on raw input: x [T,B,F0] fp32 -> spikes bf16 bits
__global__ __launch_bounds__(256) void if0_kernel(
    const float* __restrict__ x, unsigned short* __restrict__ s)
{
    const size_t id = (size_t)blockIdx.x * blockDim.x + threadIdx.x;
    float v = 0.f;
#pragma unroll
    for (int t = 0; t < T_STEPS; ++t) {
        const size_t idx = (size_t)t * (BATCH * (size_t)F0) + id;
        v += x[idx];
        if (v >= 1.0f) { s[idx] = 0x3F80; v = 0.f; }
        else           { s[idx] = 0; }
    }
}

// BN stats over 512 rows
__global__ __launch_bounds__(256) void bn_stats(
    const float* __restrict__ z, const float* __restrict__ g,
    const float* __restrict__ be, float* __restrict__ scale,
    float* __restrict__ shift)
{
    __shared__ float ssum[4][64], ssq[4][64];
    const int l = threadIdx.x & 63;
    const int q = threadIdx.x >> 6;
    const int f = blockIdx.x * 64 + l;
    float sum = 0.f, sq = 0.f;
    for (int r = q; r < NROWS; r += 4) {
        const float v = z[(size_t)r * DIM + f];
        sum += v; sq += v * v;
    }
    ssum[q][l] = sum; ssq[q][l] = sq;
    __syncthreads();
    if (threadIdx.x < 64) {
        float ts = 0.f, tq = 0.f;
#pragma unroll
        for (int i = 0; i < 4; ++i) { ts += ssum[i][l]; tq += ssq[i][l]; }
        const float mean = ts * (1.0f / NROWS);
        const float var  = tq * (1.0f / NROWS) - mean * mean;
        const float inv  = rsqrtf(var + 1e-5f);
        const float sc   = g[f] * inv;
        scale[f] = sc;
        shift[f] = be[f] - mean * sc;
    }
}

// BN apply + IF neuron: z fp32 [T*B, D] -> spikes bf16 bits
__global__ __launch_bounds__(256) void bn_if(
    const float* __restrict__ z, const float* __restrict__ scale,
    const float* __restrict__ shift, unsigned short* __restrict__ s)
{
    const int id = blockIdx.x * blockDim.x + threadIdx.x;
    const int o  = id & (DIM - 1);
    const float sc = scale[o];
    const float sh = shift[o];
    float v = 0.f;
#pragma unroll
    for (int t = 0; t < T_STEPS; ++t) {
        const size_t idx = (size_t)t * (BATCH * DIM) + id;
        v += z[idx] * sc + sh;
        if (v >= 1.0f) { s[idx] = 0x3F80; v = 0.f; }
        else           { s[idx] = 0; }
    }
}

// Layer-2 variant: BN + IF, emit only the T-mean of spikes (bf16, k/8 exact)
__global__ __launch_bounds__(256) void bn_if_mean(
    const float* __restrict__ z, const float* __restrict__ scale,
    const float* __restrict__ shift, unsigned short* __restrict__ sbar)
{
    const int id = blockIdx.x * blockDim.x + threadIdx.x;  // b*DIM+o
    const int o  = id & (DIM - 1);
    const float sc = scale[o];
    const float sh = shift[o];
    float v = 0.f;
    int cnt = 0;
#pragma unroll
    for (int t = 0; t < T_STEPS; ++t) {
        const size_t idx = (size_t)t * (BATCH * DIM) + id;
        v += z[idx] * sc + sh;
        if (v >= 1.0f) { cnt++; v = 0.f; }
    }
    sbar[id] = bf16_rne((float)cnt * 0.125f);
}

extern "C" void kernel_launch(void* const* d_in, const int* in_sizes, int n_in,
                              void* d_out, int out_size, void* d_ws, size_t ws_size,
                              hipStream_t stream)
{
    const float* x    = (const float*)d_in[0];
    const float* W0   = (const float*)d_in[1];
    const float* b0   = (const float*)d_in[2];
    const float* g0   = (const float*)d_in[3];
    const float* be0  = (const float*)d_in[4];
    const float* W1   = (const float*)d_in[5];
    const float* b1   = (const float*)d_in[6];
    const float* g1   = (const float*)d_in[7];
    const float* be1  = (const float*)d_in[8];
    const float* W2   = (const float*)d_in[9];
    const float* b2   = (const float*)d_in[10];
    const float* g2   = (const float*)d_in[11];
    const float* be2  = (const float*)d_in[12];
    const float* Wout = (const float*)d_in[13];
    const float* bout = (const float*)d_in[14];
    float* out = (float*)d_out;
    (void)in_sizes; (void)n_in; (void)out_size; (void)ws_size;

    char* ws = (char*)d_ws;
    size_t off = 0;
    auto alloc = [&](size_t nbytes) {
        char* p = ws + off;
        off = (off + nbytes + 255) & ~(size_t)255;
        return p;
    };
    unsigned short* s0 = (unsigned short*)alloc((size_t)NROWS * F0 * 2);  // 33.5 MB
    unsigned short* s1 = (unsigned short*)alloc((size_t)NROWS * DIM * 2);
    unsigned short* s2 = (unsigned short*)alloc((size_t)NROWS * DIM * 2);
    unsigned short* sb = (unsigned short*)alloc((size_t)128 * DIM * 2);   // 128-row pad
    float* z    = (float*)alloc((size_t)NROWS * DIM * 4);
    float* part = (float*)alloc((size_t)16 * NROWS * DIM * 4);            // 67 MB (KS<=16)
    float* scale = (float*)alloc(DIM * 4);
    float* shift = (float*)alloc(DIM * 4);

    const int MN = NROWS * DIM;

    // sn0
    if0_kernel<<<(BATCH * (size_t)F0) / 256, 256, 0, stream>>>(x, s0);

    // layer 0: K=32768, KS=16  (grid 4*16*16=1024, %8==0)
    gemm_splitk<<<dim3(NROWS / BM, DIM / BN, 16), 256, 0, stream>>>(
        s0, W0, part, NROWS, DIM, F0, F0 / 16, DIM);
    reduce_bias<<<MN / 4 / 256, 256, 0, stream>>>(part, b0, z, 16, MN, DIM);
    bn_stats<<<DIM / 64, 256, 0, stream>>>(z, g0, be0, scale, shift);
    bn_if<<<(BATCH * DIM) / 256, 256, 0, stream>>>(z, scale, shift, s1);

    // layer 1: K=2048, KS=8  (grid 4*16*8=512)
    gemm_splitk<<<dim3(NROWS / BM, DIM / BN, 8), 256, 0, stream>>>(
        s1, W1, part, NROWS, DIM, DIM, DIM / 8, DIM);
    reduce_bias<<<MN / 4 / 256, 256, 0, stream>>>(part, b1, z, 8, MN, DIM);
    bn_stats<<<DIM / 64, 256, 0, stream>>>(z, g1, be1, scale, shift);
    bn_if<<<(BATCH * DIM) / 256, 256, 0, stream>>>(z, scale, shift, s2);

    // layer 2: fused bn+if+mean (no s3/sbar round-trip)
    gemm_splitk<<<dim3(NROWS / BM, DIM / BN, 8), 256, 0, stream>>>(
        s2, W2, part, NROWS, DIM, DIM, DIM / 8, DIM);
    reduce_bias<<<MN / 4 / 256, 256, 0, stream>>>(part, b2, z, 8, MN, DIM);
    bn_stats<<<DIM / 64, 256, 0, stream>>>(z, g2, be2, scale, shift);
    bn_if_mean<<<(BATCH * DIM) / 256, 256, 0, stream>>>(z, scale, shift, sb);

    // readout: [64,2048] x [1000,2048]^T, KS=4 (grid 1*8*4=32)
    gemm_splitk<<<dim3(1, (NC + BN - 1) / BN, 4), 256, 0, stream>>>(
        sb, Wout, part, BATCH, NC, DIM, DIM / 4, NC);
    reduce_bias<<<(BATCH * NC / 4 + 255) / 256, 256, 0, stream>>>(
        part, bout, out, 4, BATCH * NC, NC);
}